// Round 23
// baseline (136.203 us; speedup 1.0000x reference)
//
#include <hip/hip_runtime.h>
#include <hip/hip_bf16.h>
#include <hip/hip_fp16.h>

#define TLEN 16000
#define NPSI 36
#define NBATCH 64
#define NOUT 250
#define NCH 37
#define DHALF 176            // Gaussian lowpass half-width (6.05 sigma, sigma_t=29.1)
#define KMAX 8000
#define TWO_PI 6.283185307179586

__device__ __forceinline__ int brev7(int q){ return (int)(__brev((unsigned)q) >> 25); }
__device__ __forceinline__ int drev125(int p){
    return (p % 5) * 25 + ((p / 5) % 5) * 5 + (p / 25);
}
__device__ __forceinline__ float lo2f(__half2 v){ return __low2float(v); }
__device__ __forceinline__ float hi2f(__half2 v){ return __high2float(v); }
__device__ __forceinline__ __half2 pk2(float r, float i){
    return __halves2half2(__float2half(r), __float2half(i));
}

// ---- K1a: radix-5 over n1 for 16 n2-rows + W16000 twiddle (512 blocks) ---
__global__ __launch_bounds__(256) void k_ffta(const float* __restrict__ x,
                                              float2* __restrict__ Gtmp){
    __shared__ float xr[16 * 126], xi[16 * 126];
    __shared__ float w125r[125], w125i[125];  // e^{-2pi j/125}
    __shared__ float w16r[125],  w16i[125];   // e^{-2pi j/16000}
    __shared__ float w128r[128], w128i[128];  // e^{-2pi j/128}
    const int b = blockIdx.x >> 3, g = blockIdx.x & 7, row0 = 16 * g;
    const int tid = threadIdx.x;

    for (int j = tid; j < 125; j += 256){
        double a = -TWO_PI * (double)j / 125.0;
        w125r[j] = (float)cos(a); w125i[j] = (float)sin(a);
        double a2 = -TWO_PI * (double)j / 16000.0;
        w16r[j] = (float)cos(a2); w16i[j] = (float)sin(a2);
    }
    for (int j = tid; j < 128; j += 256){
        double a = -TWO_PI * (double)j / 128.0;
        w128r[j] = (float)cos(a); w128i[j] = (float)sin(a);
    }
    for (int i = tid; i < 16 * 125; i += 256){
        int n1 = i >> 4, lr = i & 15;
        xr[lr * 126 + n1] = x[b * TLEN + 128 * n1 + row0 + lr];
        xi[lr * 126 + n1] = 0.0f;
    }
    int f = 1;
    for (int s = 25; s >= 1; s /= 5, f *= 5){
        __syncthreads();
        for (int task = tid; task < 25 * 16; task += 256){
            int u = task >> 4, lr = task & 15;
            int blk = u / s, m = u - blk * s;
            int base = lr * 126 + blk * 5 * s + m;
            float vr[5], vi[5];
            #pragma unroll
            for (int r = 0; r < 5; ++r){ vr[r] = xr[base + r * s]; vi[r] = xi[base + r * s]; }
            #pragma unroll
            for (int q = 0; q < 5; ++q){
                float cr = vr[0], ci = vi[0];
                #pragma unroll
                for (int r = 1; r < 5; ++r){
                    int w5 = 25 * ((q * r) % 5);
                    float wr = w125r[w5], wi = w125i[w5];
                    cr += vr[r] * wr - vi[r] * wi;
                    ci += vr[r] * wi + vi[r] * wr;
                }
                int jt = (m * q * f) % 125;
                float tr = w125r[jt], ti = w125i[jt];
                xr[base + q * s] = cr * tr - ci * ti;
                xi[base + q * s] = cr * ti + ci * tr;
            }
        }
    }
    __syncthreads();
    for (int i = tid; i < 125 * 16; i += 256){
        int p = i >> 4, lr = i & 15;
        int n2 = row0 + lr;
        int m = drev125(p);
        int a = m * n2;
        int qq = a / 125, rr = a - qq * 125;
        float tr = w16r[rr] * w128r[qq] - w16i[rr] * w128i[qq];
        float ti = w16r[rr] * w128i[qq] + w16i[rr] * w128r[qq];
        float ar = xr[lr * 126 + p], ai = xi[lr * 126 + p];
        Gtmp[((size_t)b * 125 + p) * 128 + n2] =
            make_float2(ar * tr - ai * ti, ar * ti + ai * tr);
    }
}

// ---- K1b: radix-2 over n2 for 5 phys cols (1600 blocks, 128 thr) ---------
__global__ __launch_bounds__(128) void k_fftb(const float2* __restrict__ Gtmp,
                                              float2* __restrict__ Xf){
    __shared__ float gr[128 * 5], gi[128 * 5];
    __shared__ float w128r[128], w128i[128];
    const int b = blockIdx.x / 25, p0 = (blockIdx.x % 25) * 5;
    const int tid = threadIdx.x;
    for (int j = tid; j < 128; j += 128){
        double a = -TWO_PI * (double)j / 128.0;
        w128r[j] = (float)cos(a); w128i[j] = (float)sin(a);
    }
    for (int i = tid; i < 5 * 128; i += 128){
        int ml = i >> 7, n2 = i & 127;
        float2 v = Gtmp[((size_t)b * 125 + p0 + ml) * 128 + n2];
        gr[n2 * 5 + ml] = v.x; gi[n2 * 5 + ml] = v.y;
    }
    for (int span = 64; span >= 1; span >>= 1){
        __syncthreads();
        for (int idx = tid; idx < 320; idx += 128){
            int u = idx / 5, ml = idx - u * 5;
            int blkq = u / span, mm = u % span;
            int i0 = (blkq * 2 * span + mm) * 5 + ml, i1 = i0 + span * 5;
            float ar = gr[i0], ai = gi[i0], br = gr[i1], bi = gi[i1];
            gr[i0] = ar + br; gi[i0] = ai + bi;
            float dr = ar - br, di = ai - bi;
            int jt = mm * (64 / span);
            gr[i1] = dr * w128r[jt] - di * w128i[jt];
            gi[i1] = dr * w128i[jt] + di * w128r[jt];
        }
    }
    __syncthreads();
    for (int idx = tid; idx < 320; idx += 128){
        int u = idx / 5, ml = idx - u * 5;
        int ad = (2 * u) * 5 + ml;
        int k = drev125(p0 + ml) + 125 * brev7(2 * u);
        Xf[(size_t)b * KMAX + k] = make_float2(gr[ad], gi[ad]);
    }
}

// radix-4 butterfly on register quads (DIF levels S, S/2; plus sign)
#define R4BODY(Ar,Ai,Br_,Bi_,Cr,Ci,Dr,Di,w1r,w1i,w2r,w2i)                   \
    {                                                                        \
        float A1r = Ar + Cr, A1i = Ai + Ci;                                  \
        float t1r = Ar - Cr, t1i = Ai - Ci;                                  \
        float C1r = t1r * w1r - t1i * w1i, C1i = t1r * w1i + t1i * w1r;      \
        float B1r = Br_ + Dr, B1i = Bi_ + Di;                                \
        float t2r = Br_ - Dr, t2i = Bi_ - Di;                                \
        float t3r = -t2i, t3i = t2r;                                         \
        float D1r = t3r * w1r - t3i * w1i, D1i = t3r * w1i + t3i * w1r;      \
        Ar = A1r + B1r; Ai = A1i + B1i;                                      \
        float u1r = A1r - B1r, u1i = A1i - B1i;                              \
        Br_ = u1r * w2r - u1i * w2i; Bi_ = u1r * w2i + u1i * w2r;            \
        Cr = C1r + D1r; Ci = C1i + D1i;                                      \
        float u2r = C1r - D1r, u2i = C1i - D1i;                              \
        Dr = u2r * w2r - u2i * w2i; Di = u2r * w2i + u2i * w2r;              \
    }

// ---- env body: round-22 structure; first two radix-4 passes merged into
// one register-resident radix-16 pass (LQ>=5) ------------------------------
template<int P5, int LQ>
__device__ __forceinline__ void env_body(const float2* __restrict__ Xfb,
                                         float* __restrict__ Schan,
                                         int fi, int b, int tid,
                                         __half2* Bc,
                                         float* wPr, float* wPi,
                                         float* wNr, float* wNi,
                                         float* wQr, float* wQi,
                                         float* w5tr, float* w5ti,
                                         float* hfull, int* drevT, float* sred){
    constexpr int Q = 1 << LQ;
    constexpr int N = P5 * Q;
    constexpr int D = TLEN / N;
    constexpr int S1 = P5 / 5;
    constexpr int EPT = (LQ & 1) ? 2 : 4;             // elems/task in final pass
    constexpr int NTASK = N / EPT;
    constexpr int NFP = (NTASK + 511) / 512;
    __half* Mag = reinterpret_cast<__half*>(Bc);      // reuses Bc after final pass

    const double xi_d = 0.35 * exp2(-(double)fi / 6.0);
    const double r_d  = exp2(1.0 / 6.0);
    const double sig_d = xi_d * (r_d - 1.0) / (r_d + 1.0);
    const float xi = (float)xi_d;
    const float centerT = (float)(xi_d * (double)TLEN);
    const float sigT = (float)(sig_d * (double)TLEN);
    int klo = (int)floorf(centerT - 5.0f * sigT); if (klo < 1) klo = 1;
    int khi = (int)ceilf(centerT + 5.0f * sigT);  if (khi > KMAX - 1) khi = KMAX - 1;
    const float inv2s2 = (float)(1.0 / (2.0 * sig_d * sig_d));

    for (int j = tid; j < P5; j += 512){
        double a = TWO_PI * (double)j / (double)P5;
        wPr[j] = (float)cos(a); wPi[j] = (float)sin(a);
        double a2 = TWO_PI * (double)j / (double)N;
        wNr[j] = (float)cos(a2); wNi[j] = (float)sin(a2);
        drevT[j] = (P5 == 125) ? drev125(j) : ((j % 5) * 5 + j / 5);
    }
    for (int j = tid; j < Q; j += 512){
        double a = TWO_PI * (double)j / (double)Q;
        wQr[j] = (float)cos(a); wQi[j] = (float)sin(a);
    }
    for (int j = tid; j < 25; j += 512){
        double a = TWO_PI * (double)(((j / 5) * (j % 5)) % 5) / 5.0;   // e^{+2pi(qr%5)/5}
        w5tr[j] = (float)cos(a); w5ti[j] = (float)sin(a);
    }
    for (int j = tid; j <= 2 * DHALF; j += 512){
        double st = 1.0 / (TWO_PI * (0.35 / 64.0));
        double dd = (double)(j - DHALF);
        hfull[j] = (float)((0.35 / 64.0) * sqrt(TWO_PI) * exp(-0.5 * dd * dd / (st * st)));
    }
    __syncthreads();
    // ---- radix-5 stage 1 over j, FUSED with psi-weighted global init -----
    for (int task = tid; task < S1 * Q; task += 512){
        int m = task >> LQ, k2 = task & (Q - 1);
        float vr[5], vi[5];
        #pragma unroll
        for (int r = 0; r < 5; ++r){
            int gk = k2 + ((m + r * S1) << LQ);
            float ur = 0.0f, ui = 0.0f;
            if (gk >= klo && gk <= khi){
                float fr = (float)gk * (1.0f / (float)TLEN);
                float d = fr - xi;
                float p = __expf(-d * d * inv2s2) * (1.0f / (float)TLEN);
                float2 Xv = Xfb[gk];
                ur = Xv.x * p; ui = Xv.y * p;
            }
            vr[r] = ur; vi[r] = ui;
        }
        int base = m * Q + k2;
        #pragma unroll
        for (int q = 0; q < 5; ++q){
            float cr = vr[0], ci = vi[0];
            #pragma unroll
            for (int r = 1; r < 5; ++r){
                float wr = w5tr[q * 5 + r], wi = w5ti[q * 5 + r];
                cr += vr[r] * wr - vi[r] * wi;
                ci += vr[r] * wi + vi[r] * wr;
            }
            int jt = m * q;                   // f = 1
            float tr = wPr[jt], ti = wPi[jt];
            Bc[base + q * S1 * Q] = pk2(cr * tr - ci * ti, cr * ti + ci * tr);
        }
    }
    // ---- middle radix-5 stage (P5=125 only): s=5, f=5 --------------------
    if (P5 == 125){
        __syncthreads();
        for (int task = tid; task < 25 * Q; task += 512){
            int u = task >> LQ, k2 = task & (Q - 1);
            int blk = u / 5, m = u - blk * 5;
            int base = (blk * 25 + m) * Q + k2;
            float vr[5], vi[5];
            #pragma unroll
            for (int r = 0; r < 5; ++r){
                __half2 v = Bc[base + r * 5 * Q];
                vr[r] = lo2f(v); vi[r] = hi2f(v);
            }
            #pragma unroll
            for (int q = 0; q < 5; ++q){
                float cr = vr[0], ci = vi[0];
                #pragma unroll
                for (int r = 1; r < 5; ++r){
                    float wr = w5tr[q * 5 + r], wi = w5ti[q * 5 + r];
                    cr += vr[r] * wr - vi[r] * wi;
                    ci += vr[r] * wi + vi[r] * wr;
                }
                int jt = m * q * 5;           // < 125
                float tr = wPr[jt], ti = wPi[jt];
                Bc[base + q * 5 * Q] = pk2(cr * tr - ci * ti, cr * ti + ci * tr);
            }
        }
    }
    // ---- final radix-5 stage fused with W_N^{+k2 n1} output twiddle ------
    __syncthreads();
    for (int task = tid; task < S1 * Q; task += 512){
        int u = task >> LQ, k2 = task & (Q - 1);
        int base = (u * 5) * Q + k2;
        float vr[5], vi[5];
        #pragma unroll
        for (int r = 0; r < 5; ++r){
            __half2 v = Bc[base + r * Q];
            vr[r] = lo2f(v); vi[r] = hi2f(v);
        }
        #pragma unroll
        for (int q = 0; q < 5; ++q){
            float cr = vr[0], ci = vi[0];
            #pragma unroll
            for (int r = 1; r < 5; ++r){
                float wr = w5tr[q * 5 + r], wi = w5ti[q * 5 + r];
                cr += vr[r] * wr - vi[r] * wi;
                ci += vr[r] * wi + vi[r] * wr;
            }
            int n1 = drevT[5 * u + q];
            int a = k2 * n1;                  // < N = P5*qq + rr
            int qq = a / P5, rr = a - qq * P5;
            float tr = wQr[qq] * wNr[rr] - wQi[qq] * wNi[rr];
            float ti = wQr[qq] * wNi[rr] + wQi[qq] * wNr[rr];
            Bc[base + q * Q] = pk2(cr * tr - ci * ti, cr * ti + ci * tr);
        }
    }
    // ---- k2-FFT: radix-16 register pass (levels Q/2..Q/16) for LQ>=5 -----
    if (LQ >= 5){
        constexpr int ST = Q / 16;            // stride between the 16 elements
        __syncthreads();
        for (int task = tid; task < P5 * ST; task += 512){
            int prow = task / ST, m = task - (task / ST) * ST;
            int base = prow * Q + m;
            float er[16], ei[16];
            #pragma unroll
            for (int j = 0; j < 16; ++j){
                __half2 v = Bc[base + j * ST];
                er[j] = lo2f(v); ei[j] = hi2f(v);
            }
            // pass A: levels (Q/2, Q/4); butterflies {j0, j0+4, j0+8, j0+12}
            #pragma unroll
            for (int j0 = 0; j0 < 4; ++j0){
                int jt1 = m + j0 * ST;        // = m_cur * (Q/2)/(Q/2)
                float w1r = wQr[jt1], w1i = wQi[jt1];
                float w2r = wQr[2 * jt1], w2i = wQi[2 * jt1];
                R4BODY(er[j0], ei[j0], er[j0+4], ei[j0+4],
                       er[j0+8], ei[j0+8], er[j0+12], ei[j0+12],
                       w1r, w1i, w2r, w2i)
            }
            // pass B: levels (Q/8, Q/16); windows {4k..4k+3}, twiddle 4m
            {
                int jt1 = 4 * m;
                float w1r = wQr[jt1], w1i = wQi[jt1];
                float w2r = wQr[2 * jt1], w2i = wQi[2 * jt1];
                #pragma unroll
                for (int k = 0; k < 4; ++k){
                    R4BODY(er[4*k], ei[4*k], er[4*k+1], ei[4*k+1],
                           er[4*k+2], ei[4*k+2], er[4*k+3], ei[4*k+3],
                           w1r, w1i, w2r, w2i)
                }
            }
            #pragma unroll
            for (int j = 0; j < 16; ++j)
                Bc[base + j * ST] = pk2(er[j], ei[j]);
        }
        // LQ==7 has one remaining radix-4 level pair (4,2)
        if (LQ == 7){
            __syncthreads();
            for (int task = tid; task < P5 * (Q / 4); task += 512){
                int prow = task / (Q / 4), v = task & (Q / 4 - 1);
                int blkq = v / 2, m = v & 1;          // Sp=4, half=2
                int base = prow * Q + blkq * 8 + m;
                __half2 vA = Bc[base],     vB = Bc[base + 2];
                __half2 vC = Bc[base + 4], vD = Bc[base + 6];
                float Ar = lo2f(vA), Ai = hi2f(vA);
                float B2r = lo2f(vB), B2i = hi2f(vB);
                float Cr = lo2f(vC), Ci = hi2f(vC);
                float D2r = lo2f(vD), D2i = hi2f(vD);
                int jt1 = m * (Q / 8);                // m * (Q/2)/4
                float w1r = wQr[jt1], w1i = wQi[jt1];
                float w2r = wQr[2 * jt1], w2i = wQi[2 * jt1];
                R4BODY(Ar, Ai, B2r, B2i, Cr, Ci, D2r, D2i, w1r, w1i, w2r, w2i)
                Bc[base] = pk2(Ar, Ai);
                Bc[base + 2] = pk2(B2r, B2i);
                Bc[base + 4] = pk2(Cr, Ci);
                Bc[base + 6] = pk2(D2r, D2i);
            }
        }
    } else {                                  // LQ==4: original single pass (8,4)
        __syncthreads();
        for (int task = tid; task < P5 * (Q / 4); task += 512){
            int prow = task / (Q / 4), v = task & (Q / 4 - 1);
            int blkq = v / 4, m = v & 3;              // Sp=8, half=4
            int base = prow * Q + blkq * 16 + m;
            __half2 vA = Bc[base],     vB = Bc[base + 4];
            __half2 vC = Bc[base + 8], vD = Bc[base + 12];
            float Ar = lo2f(vA), Ai = hi2f(vA);
            float B2r = lo2f(vB), B2i = hi2f(vB);
            float Cr = lo2f(vC), Ci = hi2f(vC);
            float D2r = lo2f(vD), D2i = hi2f(vD);
            int jt1 = m * (Q / 16);                   // m * (Q/2)/8
            float w1r = wQr[jt1], w1i = wQi[jt1];
            float w2r = wQr[2 * jt1], w2i = wQi[2 * jt1];
            R4BODY(Ar, Ai, B2r, B2i, Cr, Ci, D2r, D2i, w1r, w1i, w2r, w2i)
            Bc[base] = pk2(Ar, Ai);
            Bc[base + 4] = pk2(B2r, B2i);
            Bc[base + 8] = pk2(Cr, Ci);
            Bc[base + 12] = pk2(D2r, D2i);
        }
    }
    __syncthreads();
    // ---- FINAL butterfly level fused with |z| (twiddles are exactly 1) ---
    float magf[NFP][EPT];
    #pragma unroll
    for (int i = 0; i < NFP; ++i){
        int task = tid + 512 * i;
        if (task < NTASK){
            if (LQ & 1){                      // leftover span-1 radix-2
                int p = task / (Q / 2), u = task - p * (Q / 2);
                int i0 = p * Q + 2 * u;
                __half2 v0 = Bc[i0], v1 = Bc[i0 + 1];
                float ar = lo2f(v0), ai = hi2f(v0);
                float br2 = lo2f(v1), bi2 = hi2f(v1);
                float o0r = ar + br2, o0i = ai + bi2;
                float o1r = ar - br2, o1i = ai - bi2;
                magf[i][0] = sqrtf(o0r * o0r + o0i * o0i);
                magf[i][1] = sqrtf(o1r * o1r + o1i * o1i);
            } else {                          // final radix-4 (Sp=2, half=1, m=0)
                int prow = task / (Q / 4), v = task & (Q / 4 - 1);
                int base = prow * Q + 4 * v;
                __half2 v0 = Bc[base], v1 = Bc[base + 1];
                __half2 v2 = Bc[base + 2], v3 = Bc[base + 3];
                float Ar = lo2f(v0), Ai = hi2f(v0);
                float B2r = lo2f(v1), B2i = hi2f(v1);
                float Cr = lo2f(v2), Ci = hi2f(v2);
                float D2r = lo2f(v3), D2i = hi2f(v3);
                float A1r = Ar + Cr, A1i = Ai + Ci;
                float C1r = Ar - Cr, C1i = Ai - Ci;
                float B1r = B2r + D2r, B1i = B2i + D2i;
                float t2r = B2r - D2r, t2i = B2i - D2i;
                float D1r = -t2i, D1i = t2r;          // * i (plus sign)
                float o0r = A1r + B1r, o0i = A1i + B1i;
                float o1r = A1r - B1r, o1i = A1i - B1i;
                float o2r = C1r + D1r, o2i = C1i + D1i;
                float o3r = C1r - D1r, o3i = C1i - D1i;
                magf[i][0] = sqrtf(o0r * o0r + o0i * o0i);
                magf[i][1] = sqrtf(o1r * o1r + o1i * o1i);
                magf[i][2] = sqrtf(o2r * o2r + o2i * o2i);
                magf[i][3] = sqrtf(o3r * o3r + o3i * o3i);
            }
        }
    }
    __syncthreads();                          // all final-level reads done
    // ---- scatter mags to padded-linear Mag (aliases Bc): np + (np>>4) ----
    #pragma unroll
    for (int i = 0; i < NFP; ++i){
        int task = tid + 512 * i;
        if (task < NTASK){
            int row, s0;
            if (LQ & 1){ row = task / (Q / 2); s0 = 2 * (task - row * (Q / 2)); }
            else       { row = task / (Q / 4); s0 = 4 * (task & (Q / 4 - 1)); }
            #pragma unroll
            for (int e = 0; e < EPT; ++e){
                int slot = s0 + e;
                int n2 = (int)(__brev((unsigned)slot) >> (32 - LQ));
                int np = drevT[row] + P5 * n2;
                Mag[np + (np >> 4)] = __float2half(magf[i][e]);
            }
        }
    }
    __syncthreads();
    // ---- conv: S1[t] = D * sum_n phi(64t - Dn) Mag[n], 2-way tap split ---
    float acc = 0.0f;
    if (tid < 500){
        int t = tid - 250 * (tid / 250);
        int q = tid / 250;
        int m0 = 64 * t;
        int lo = m0 - DHALF;
        int nlo = (lo >= 0) ? ((lo + D - 1) / D) : -((-lo) / D);
        int nhi = (m0 + DHALF) / D;
        int n = nlo + q;
        if (n <= nhi){
            int np = n % N; if (np < 0) np += N;
            int d = m0 - D * n + DHALF;
            for (; n <= nhi; n += 2){
                acc += hfull[d] * __half2float(Mag[np + (np >> 4)]);
                d -= 2 * D;
                np += 2; if (np >= N) np -= N;
            }
        }
        sred[tid] = acc;
    }
    __syncthreads();
    if (tid < 250)
        Schan[(b * NCH + 1 + fi) * NOUT + tid] = (sred[tid] + sred[tid + 250]) * (float)D;
}

// ---- K2: all 36 channels + S0 in one 2368-block dispatch (512 thr) -------
__global__ __launch_bounds__(512, 4) void k_env_all(const float* __restrict__ x,
                                                    const float2* __restrict__ Xf,
                                                    float* __restrict__ Schan){
    __shared__ __half2 Bc[8000];               // complex plane; Mag aliases it
    __shared__ float wPr[125], wPi[125];
    __shared__ float wNr[125], wNi[125];
    __shared__ float wQr[128], wQi[128];
    __shared__ float w5tr[25], w5ti[25];
    __shared__ float hfull[2 * DHALF + 1];
    __shared__ int   drevT[125];
    __shared__ float sred[500];

    const int bi = blockIdx.x;
    const int tid = threadIdx.x;
    if (bi < 448){                         // N=8000, D=2,  fi 0-6
        int fi = bi >> 6, b = bi & 63;
        env_body<125, 6>(Xf + (size_t)b * KMAX, Schan, fi, b, tid, Bc,
                         wPr, wPi, wNr, wNi, wQr, wQi, w5tr, w5ti, hfull, drevT, sred);
    } else if (bi < 640){                  // N=4000, D=4,  fi 7-9
        int t = bi - 448;
        int fi = 7 + (t >> 6), b = t & 63;
        env_body<125, 5>(Xf + (size_t)b * KMAX, Schan, fi, b, tid, Bc,
                         wPr, wPi, wNr, wNi, wQr, wQi, w5tr, w5ti, hfull, drevT, sred);
    } else if (bi < 1088){                 // N=3200, D=5,  fi 10-16
        int t = bi - 640;
        int fi = 10 + (t >> 6), b = t & 63;
        env_body<25, 7>(Xf + (size_t)b * KMAX, Schan, fi, b, tid, Bc,
                        wPr, wPi, wNr, wNi, wQr, wQi, w5tr, w5ti, hfull, drevT, sred);
    } else if (bi < 1408){                 // N=2000, D=8,  fi 17-21
        int t = bi - 1088;
        int fi = 17 + (t >> 6), b = t & 63;
        env_body<125, 4>(Xf + (size_t)b * KMAX, Schan, fi, b, tid, Bc,
                         wPr, wPi, wNr, wNi, wQr, wQi, w5tr, w5ti, hfull, drevT, sred);
    } else if (bi < 2304){                 // N=1600, D=10, fi 22-35
        int t = bi - 1408;
        int fi = 22 + (t >> 6), b = t & 63;
        env_body<25, 6>(Xf + (size_t)b * KMAX, Schan, fi, b, tid, Bc,
                        wPr, wPi, wNr, wNi, wQr, wQi, w5tr, w5ti, hfull, drevT, sred);
    } else {                               // S0 channel, one block per batch
        int b = bi - 2304;
        const float* xb = x + (size_t)b * TLEN;
        for (int j = tid; j <= 2 * DHALF; j += 512){
            double st = 1.0 / (TWO_PI * (0.35 / 64.0));
            double dd = (double)(j - DHALF);
            hfull[j] = (float)((0.35 / 64.0) * sqrt(TWO_PI) * exp(-0.5 * dd * dd / (st * st)));
        }
        __syncthreads();
        float acc = 0.0f;
        if (tid < 500){
            int t = tid - 250 * (tid / 250);
            int q = tid / 250;
            int m0 = 64 * t;
            for (int j = q; j <= 2 * DHALF; j += 2){
                int n = m0 - DHALF + j;
                if (n < 0) n += TLEN; else if (n >= TLEN) n -= TLEN;
                acc += hfull[j] * xb[n];
            }
            sred[tid] = acc;
        }
        __syncthreads();
        if (tid < 250)
            Schan[(b * NCH + 0) * NOUT + tid] = sred[tid] + sred[tid + 250];
    }
}

// ---- K4: channel-group means -> f32 --------------------------------------
__global__ __launch_bounds__(256) void k_reduce(const float* __restrict__ Schan,
                                                float* __restrict__ out){
    int o = blockIdx.x * 256 + threadIdx.x;
    if (o >= NBATCH * 3 * NOUT) return;
    int b = o / (3 * NOUT);
    int rem = o - b * 3 * NOUT;
    int g = rem / NOUT;
    int t = rem - g * NOUT;
    int c0 = (g == 0) ? 0 : (g == 1 ? 12 : 24);
    int c1 = (g == 0) ? 12 : (g == 1 ? 24 : 37);
    float s = 0.0f;
    for (int c = c0; c < c1; ++c) s += Schan[(b * NCH + c) * NOUT + t];
    out[o] = s / (float)(c1 - c0);
}

__global__ void k_fill_f32(float* out, int n, float v){
    int i = blockIdx.x * 256 + threadIdx.x;
    if (i < n) out[i] = v;
}

extern "C" void kernel_launch(void* const* d_in, const int* in_sizes, int n_in,
                              void* d_out, int out_size, void* d_ws, size_t ws_size,
                              hipStream_t stream) {
    const float* x = (const float*)d_in[0];
    float* out = (float*)d_out;
    const size_t xf_bytes = (size_t)NBATCH * KMAX * sizeof(float2);          // 4.10 MB
    const size_t schan_bytes = (size_t)NBATCH * NCH * NOUT * sizeof(float);  // 2.37 MB
    const size_t gtmp_bytes = (size_t)NBATCH * 16000 * sizeof(float2);       // 8.19 MB
    if (ws_size < xf_bytes + schan_bytes + gtmp_bytes){
        k_fill_f32<<<(out_size + 255) / 256, 256, 0, stream>>>(out, out_size, 800.0f);
        return;
    }
    float2* Xf = (float2*)d_ws;
    float* Schan = (float*)((char*)d_ws + xf_bytes);
    float2* Gtmp = (float2*)((char*)d_ws + xf_bytes + schan_bytes);

    k_ffta<<<NBATCH * 8, 256, 0, stream>>>(x, Gtmp);
    k_fftb<<<NBATCH * 25, 128, 0, stream>>>(Gtmp, Xf);
    k_env_all<<<2368, 512, 0, stream>>>(x, Xf, Schan);
    k_reduce<<<(NBATCH * 3 * NOUT + 255) / 256, 256, 0, stream>>>(Schan, out);
}